// Round 7
// baseline (305.450 us; speedup 1.0000x reference)
//
#include <hip/hip_runtime.h>
#include <stdint.h>

// B=4, S=2048, D=1024, H=16, Hd=64, M=8192.
// Pipeline: cast x -> bf16; merged W^T casts; QKV GEMM (256^2 tile, 2-buffer
// depth-1 pipeline, fragment-major LDS, 2 blocks/CU); V transpose; flash attn
// (S^T = K@Q^T key-permutation trick); O-projection GEMM (fp32 out).
// R2: XCD decode cuts attn FETCH 139->24.6 MB.
// R3: setprio hurts lockstep attn loop (m190); GEMM XCD swizzle helps.
// R4: 256^2 counted-vmcnt QKV at 23% MfmaUtil; blamed 8-way LDS conflicts.
// R5: fragment-major LDS -> conflicts 4.7M -> 0, but dur 86->80.8 only.
//     Model: no pipe >25% busy, ~3030 cyc/K-step vs <1k required. True stall:
//     96KB LDS -> 1 block/CU -> 2 waves/SIMD; lockstep barrier per K-step has
//     no TLP to hide drains; 384 blocks at 1/CU = 1.5 rounds (25% idle).
// R6: 2 buffers (64KB), depth-1 prefetch -> 2 blocks/CU, 4 waves/SIMD, all
//     384 blocks co-resident. TLP (m114) absorbs the per-iteration drain.
//     (R6 bench never ran: GPU acquisition timeout. Resubmitted unchanged.)

typedef float f32x4 __attribute__((ext_vector_type(4)));
typedef __bf16 bf16x4 __attribute__((ext_vector_type(4)));
typedef __bf16 bf16x8 __attribute__((ext_vector_type(8)));
typedef uint32_t u32x4 __attribute__((ext_vector_type(4)));

#define MFMA16(a, b, c) __builtin_amdgcn_mfma_f32_16x16x32_bf16((a), (b), (c), 0, 0, 0)

// Q pre-scale: log2(e)/8 so attn does p = exp2(Q'.K) = e^{QK/8} (unnormalized)
#define QSCALE 0.1803368801111204f

__device__ __forceinline__ unsigned short f2bf(float f) {
  union { float f; uint32_t u; } c; c.f = f;
  uint32_t u = c.u;
  return (unsigned short)((u + 0x7fffu + ((u >> 16) & 1u)) >> 16);  // RNE
}

// ---------------------------------------------------------------- casts
__global__ __launch_bounds__(256) void cast_x_kernel(const float* __restrict__ in,
                                                     unsigned short* __restrict__ out,
                                                     int n4) {
  int i = blockIdx.x * 256 + threadIdx.x;
  if (i >= n4) return;
  float4 v = ((const float4*)in)[i];
  ushort4 o;
  o.x = f2bf(v.x); o.y = f2bf(v.y); o.z = f2bf(v.z); o.w = f2bf(v.w);
  ((ushort4*)out)[i] = o;
}

// 4 weights [k][n] fp32 -> Wt [n][k] bf16, z selects matrix; dst contiguous.
__global__ __launch_bounds__(256) void transpose_cast4(const float* __restrict__ W0,
                                                       const float* __restrict__ W1,
                                                       const float* __restrict__ W2,
                                                       const float* __restrict__ W3,
                                                       unsigned short* __restrict__ Wt) {
  __shared__ float tile[32][33];
  const int z = blockIdx.z;
  const float* W = (z == 0) ? W0 : (z == 1) ? W1 : (z == 2) ? W2 : W3;
  unsigned short* dst = Wt + (size_t)z * 1048576;
  int k0 = blockIdx.x * 32, n0 = blockIdx.y * 32;
  int tx = threadIdx.x, ty = threadIdx.y;
#pragma unroll
  for (int i = 0; i < 32; i += 8)
    tile[ty + i][tx] = W[(size_t)(k0 + ty + i) * 1024 + n0 + tx];
  __syncthreads();
#pragma unroll
  for (int i = 0; i < 32; i += 8)
    dst[(size_t)(n0 + ty + i) * 1024 + k0 + tx] = f2bf(tile[tx][ty + i]);
}

// ---------------------------------------------------------------- QKV GEMM 256^2
// A [8192][1024] bf16, Bt [3072][1024] bf16. out = QKV bf16 base (3 x 8388608),
// scatter to [b,h,s,hd]; Q (mb==0) scaled by QSCALE.
// Fragment-major LDS (R5, zero conflicts): chunk ja = msub*64 + quad*16 + l16
// at byte ja*16 holds A[msub*16+l16][quad*8..+8); frag read = base + lane*16.
// R6: 2 buffers (64 KB) -> 2 blocks/CU, 4 waves/SIMD. Depth-1 prefetch:
// stage t+1 into buf^1 at top of iter t; vmcnt(0)+lgkmcnt(0)+barrier at end.
// Residual load latency hidden by the co-resident block's waves (TLP, m114).
__global__ __launch_bounds__(512) void gemm256_qkv(const unsigned short* __restrict__ A,
                                                   const unsigned short* __restrict__ Bt,
                                                   const float* __restrict__ b0,
                                                   const float* __restrict__ b1,
                                                   const float* __restrict__ b2,
                                                   unsigned short* __restrict__ out) {
  __shared__ unsigned short sm[2 * 16384];  // 64 KB: 2 x (A 16KB | B 16KB)
  auto lds3 = (__attribute__((address_space(3))) char*)sm;

  const int tid = threadIdx.x;
  const int wave = tid >> 6, lane = tid & 63, quad = lane >> 4, l16 = lane & 15;
  const int wm = wave >> 2, wn = wave & 3;

  // XCD-chunked decode: XCD owns 4 row-panels (A 2MB L2-resident), bx-major.
  const int id = blockIdx.x;
  const int nid = id >> 3;
  const int by = (id & 7) * 4 + (nid & 3);
  const int bx = nid >> 2;
  const int bm = by * 256, bn = bx * 256;

  // staging sources (fragment-major): wave stages msub {wave, wave+8} of A and B
  const unsigned short* gA0 = A + (size_t)(bm + wave * 16 + l16) * 1024 + quad * 8;
  const unsigned short* gA1 = gA0 + (size_t)128 * 1024;
  const unsigned short* gB0 = Bt + (size_t)(bn + wave * 16 + l16) * 1024 + quad * 8;
  const unsigned short* gB1 = gB0 + (size_t)128 * 1024;
  const int ldw = wave * 1024;  // wave's chunk-group byte offset

#define GLDS(gp, lo)                                                         \
  __builtin_amdgcn_global_load_lds(                                          \
      (const __attribute__((address_space(1))) void*)(gp),                   \
      (__attribute__((address_space(3))) void*)(lds3 + (lo)), 16, 0, 0)

#define STAGE_T(nb, kk)                                                      \
  do {                                                                       \
    GLDS(gA0 + (kk), (nb) * 32768 + ldw);                                    \
    GLDS(gA1 + (kk), (nb) * 32768 + 8192 + ldw);                             \
    GLDS(gB0 + (kk), (nb) * 32768 + 16384 + ldw);                            \
    GLDS(gB1 + (kk), (nb) * 32768 + 24576 + ldw);                            \
  } while (0)

  f32x4 acc[8][4] = {};

  STAGE_T(0, 0);
  asm volatile("s_waitcnt vmcnt(0)" ::: "memory");
  __builtin_amdgcn_s_barrier();

  for (int t = 0; t < 32; ++t) {
    const int cb = t & 1;
    if (t < 31) STAGE_T(cb ^ 1, (t + 1) * 32);

    const unsigned short* Ab = sm + cb * 16384;
    const unsigned short* Bb = Ab + 8192;

    bf16x8 af0[4], af1[4], bfv[4];
#pragma unroll
    for (int n = 0; n < 4; ++n)
      bfv[n] = *(const bf16x8*)(Bb + ((wn * 4 + n) << 9) + (lane << 3));
#pragma unroll
    for (int i = 0; i < 4; ++i)
      af0[i] = *(const bf16x8*)(Ab + ((wm * 8 + i) << 9) + (lane << 3));
#pragma unroll
    for (int i = 0; i < 4; ++i)
#pragma unroll
      for (int n = 0; n < 4; ++n)
        acc[i][n] = MFMA16(af0[i], bfv[n], acc[i][n]);
#pragma unroll
    for (int i = 0; i < 4; ++i)
      af1[i] = *(const bf16x8*)(Ab + ((wm * 8 + i + 4) << 9) + (lane << 3));
#pragma unroll
    for (int i = 0; i < 4; ++i)
#pragma unroll
      for (int n = 0; n < 4; ++n)
        acc[i + 4][n] = MFMA16(af1[i], bfv[n], acc[i + 4][n]);

    if (t < 31) {
      // t+1's loads (issued above, covered by this compute phase) must land;
      // this block's reads of buf cb drained (lgkmcnt) before t+2 re-stages cb.
      asm volatile("s_waitcnt vmcnt(0)" ::: "memory");
      asm volatile("s_waitcnt lgkmcnt(0)" ::: "memory");
      __builtin_amdgcn_s_barrier();
    }
  }
#undef STAGE_T
#undef GLDS

  // epilogue: C/D layout col=lane&15, row=quad*4+reg; scatter to [b,h,s,hd]
  const int mb = bn >> 10;  // block (256 cols) never straddles: 1024 % 256 == 0
  const float* bias = (mb == 0) ? b0 : (mb == 1 ? b1 : b2);
  const float scale = (mb == 0) ? QSCALE : 1.0f;
  unsigned short* oq = out + (size_t)mb * 8388608u;

#pragma unroll
  for (int i = 0; i < 8; ++i) {
    const int row0 = bm + wm * 128 + i * 16 + quad * 4;
#pragma unroll
    for (int n = 0; n < 4; ++n) {
      const int col = bn + wn * 64 + n * 16 + l16;
      const int cl = col & 1023;
      const float bv = bias[cl];
      const int h = cl >> 6, hd = cl & 63;
#pragma unroll
      for (int r = 0; r < 4; ++r) {
        const int rr = row0 + r;
        const int b = rr >> 11, s = rr & 2047;
        float v = (acc[i][n][r] + bv) * scale;
        oq[((size_t)(b * 16 + h) * 2048 + s) * 64 + hd] = f2bf(v);
      }
    }
  }
}

// ---------------------------------------------------------------- O-proj GEMM
// out fp32 [8192][1024], bias b0. grid 512 flat, XCD-chunked decode.
// Fragment-major LDS (same scheme as gemm256): zero-conflict frag reads.
template <int MODE>
__global__ __launch_bounds__(256) void gemm128(const unsigned short* __restrict__ A,
                                               const unsigned short* __restrict__ Bt,
                                               const float* __restrict__ b0,
                                               const float* __restrict__ b1,
                                               const float* __restrict__ b2,
                                               void* __restrict__ out) {
  constexpr int Kd = 1024;
  __shared__ unsigned short sm[8192];  // A 8KB | B 8KB
  auto lds3 = (__attribute__((address_space(3))) char*)sm;

  const int tid = threadIdx.x;
  const int wave = tid >> 6, lane = tid & 63, quad = lane >> 4, l16 = lane & 15;
  const int wm = wave >> 1, wn = wave & 1;

  const int id = blockIdx.x;
  const int nid = id >> 3;
  const int by = (id & 7) * 8 + (nid & 7);
  const int bx = nid >> 3;
  const int bm = by * 128, bn = bx * 128;

  // staging: wave stages msub {wave, wave+4} of A and B (8 subtiles each)
  const unsigned short* gA0 = A + (size_t)(bm + wave * 16 + l16) * Kd + quad * 8;
  const unsigned short* gA1 = gA0 + (size_t)64 * Kd;
  const unsigned short* gB0 = Bt + (size_t)(bn + wave * 16 + l16) * Kd + quad * 8;
  const unsigned short* gB1 = gB0 + (size_t)64 * Kd;
  const int ldw = wave * 1024;

  f32x4 acc[4][4] = {};

  for (int k0 = 0; k0 < Kd; k0 += 32) {
    __builtin_amdgcn_global_load_lds(
        (const __attribute__((address_space(1))) void*)(gA0 + k0),
        (__attribute__((address_space(3))) void*)(lds3 + ldw), 16, 0, 0);
    __builtin_amdgcn_global_load_lds(
        (const __attribute__((address_space(1))) void*)(gA1 + k0),
        (__attribute__((address_space(3))) void*)(lds3 + 4096 + ldw), 16, 0, 0);
    __builtin_amdgcn_global_load_lds(
        (const __attribute__((address_space(1))) void*)(gB0 + k0),
        (__attribute__((address_space(3))) void*)(lds3 + 8192 + ldw), 16, 0, 0);
    __builtin_amdgcn_global_load_lds(
        (const __attribute__((address_space(1))) void*)(gB1 + k0),
        (__attribute__((address_space(3))) void*)(lds3 + 12288 + ldw), 16, 0, 0);
    __syncthreads();

    bf16x8 af[4], bfv[4];
#pragma unroll
    for (int i = 0; i < 4; ++i)
      af[i] = *(const bf16x8*)(sm + ((wm * 4 + i) << 9) + (lane << 3));
#pragma unroll
    for (int n = 0; n < 4; ++n)
      bfv[n] = *(const bf16x8*)(sm + 4096 + ((wn * 4 + n) << 9) + (lane << 3));
#pragma unroll
    for (int i = 0; i < 4; ++i)
#pragma unroll
      for (int n = 0; n < 4; ++n)
        acc[i][n] = MFMA16(af[i], bfv[n], acc[i][n]);
    __syncthreads();
  }

  // epilogue: C/D layout col=lane&15, row=quad*4+reg
  const float* bias = b0;
#pragma unroll
  for (int i = 0; i < 4; ++i) {
    const int row0 = bm + wm * 64 + i * 16 + quad * 4;
#pragma unroll
    for (int n = 0; n < 4; ++n) {
      const int col = bn + wn * 64 + n * 16 + l16;
      const float bv = bias[col & 1023];
#pragma unroll
      for (int r = 0; r < 4; ++r) {
        float v = acc[i][n][r] + bv;
        ((float*)out)[(size_t)(row0 + r) * 1024 + col] = v;
      }
    }
  }
}

// ---------------------------------------------------------------- V transpose
// Vb [bh][s][64] bf16 -> VtG [bh][64][2048] bf16.
__global__ __launch_bounds__(256) void transpose_v(const unsigned short* __restrict__ Vb,
                                                   unsigned short* __restrict__ VtG) {
  __shared__ uint32_t t32[64][33];
  const int bh = blockIdx.y, s0 = blockIdx.x * 64;
  const int tid = threadIdx.x;
  const size_t hbase = (size_t)bh * 131072;
#pragma unroll
  for (int it = 0; it < 2; ++it) {
    int c = tid + it * 256;
    int sr = c >> 3, o4 = (c & 7) * 4;
    u32x4 v = *(const u32x4*)(Vb + hbase + (size_t)(s0 + sr) * 64 + o4 * 2);
    t32[sr][o4] = v[0]; t32[sr][o4 + 1] = v[1];
    t32[sr][o4 + 2] = v[2]; t32[sr][o4 + 3] = v[3];
  }
  __syncthreads();
#pragma unroll
  for (int it = 0; it < 2; ++it) {
    int c = tid + it * 256;
    int hd = c >> 3, so = (c & 7) * 8;
    int hc = hd >> 1, sh = (hd & 1) * 16;
    uint32_t w[4];
#pragma unroll
    for (int j = 0; j < 4; ++j) {
      uint32_t lo = t32[so + 2 * j][hc], hi = t32[so + 2 * j + 1][hc];
      w[j] = ((lo >> sh) & 0xffffu) | (((hi >> sh) & 0xffffu) << 16);
    }
    *(u32x4*)(VtG + hbase + (size_t)hd * 2048 + s0 + so) = *(u32x4*)w;
  }
}

// ---------------------------------------------------------------- flash attention
// Q pre-scaled. 512 flat blocks; block = (b,h) x 256 q-rows; wave = 64 q-rows
// (4 subtiles). XCD-grouped decode: bh = (id&7)*8 + ((id>>3)>>3) so all 8
// q-blocks of a head (and 8 whole heads) land on one XCD -> K/Vt L2-resident
// (proven R2/R3: FETCH 139 -> 25.7 MB). No setprio: lockstep loop (m190/R3).
// S^T = K(A) @ Q^T(B): C-layout puts col=l16=qrow, so each lane's 16 exp2'd
// scores (keys quad*4+r per subtile) form PV A-frags directly under the key
// permutation sigma(q*8+j) = st*32 + (j>>2)*16 + q*4 + (j&3); V B-frags use
// the same sigma (two contiguous b64 chunks from the Vt tile). No P in LDS.
__global__ __launch_bounds__(256, 2) void attn_kernel(const unsigned short* __restrict__ Q,
                                                      const unsigned short* __restrict__ K,
                                                      const unsigned short* __restrict__ Vt,
                                                      unsigned short* __restrict__ ctx) {
  const int tid = threadIdx.x;
  const int wave = tid >> 6, lane = tid & 63, quad = lane >> 4, l16 = lane & 15;

  const int id = blockIdx.x;
  const int bh = (id & 7) * 8 + ((id >> 3) >> 3);  // 8 heads per XCD
  const int qx = (id >> 3) & 7;

  // stride 72 ushorts = 36 dwords == 4 mod 32 -> conflict-free-ish frag reads
  // double buffer: [buf][Ks 64*72 | Vts 64*72]
  __shared__ unsigned short sm[2][2 * 64 * 72];

  const size_t hb = (size_t)bh * 131072;
  const int q0 = qx * 256 + wave * 64;

  // Q B-frags: B[k=hd][n=qrow]: lane l16 = qrow, k = quad*8+j (+32*st)
  bf16x8 qf[4][2];
#pragma unroll
  for (int qt = 0; qt < 4; ++qt)
#pragma unroll
    for (int st = 0; st < 2; ++st)
      qf[qt][st] = *(const bf16x8*)(Q + hb + (size_t)(q0 + qt * 16 + l16) * 64 + st * 32 + quad * 8);

  f32x4 o[4][4] = {};
  float lacc[4] = {0.f, 0.f, 0.f, 0.f};

  // staging: 4 x 16B chunks/thread (2 K rows-of-keys + 2 Vt rows-of-hd)
  const int c0 = tid, c1 = tid + 256;
  const unsigned short* gK0 = K + hb + (size_t)(c0 >> 3) * 64 + (c0 & 7) * 8;
  const unsigned short* gK1 = K + hb + (size_t)(c1 >> 3) * 64 + (c1 & 7) * 8;
  const unsigned short* gV0 = Vt + hb + (size_t)(c0 >> 3) * 2048 + (c0 & 7) * 8;
  const unsigned short* gV1 = Vt + hb + (size_t)(c1 >> 3) * 2048 + (c1 & 7) * 8;
  const int sKo = (c0 >> 3) * 72 + (c0 & 7) * 8;
  const int sKo1 = (c1 >> 3) * 72 + (c1 & 7) * 8;

  u32x4 pk0 = *(const u32x4*)gK0, pk1 = *(const u32x4*)gK1;
  u32x4 pv0 = *(const u32x4*)gV0, pv1 = *(const u32x4*)gV1;
  {
    unsigned short* s0b = sm[0];
    *(u32x4*)(s0b + sKo) = pk0; *(u32x4*)(s0b + sKo1) = pk1;
    *(u32x4*)(s0b + 4608 + sKo) = pv0; *(u32x4*)(s0b + 4608 + sKo1) = pv1;
  }
  __syncthreads();

  for (int kb = 0; kb < 2048; kb += 64) {
    const int cur = (kb >> 6) & 1;
    const bool more = (kb + 64) < 2048;
    if (more) {
      pk0 = *(const u32x4*)(gK0 + (size_t)(kb + 64) * 64);
      pk1 = *(const u32x4*)(gK1 + (size_t)(kb + 64) * 64);
      pv0 = *(const u32x4*)(gV0 + kb + 64);
      pv1 = *(const u32x4*)(gV1 + kb + 64);
    }
    const unsigned short* Ks = sm[cur];
    const unsigned short* Vts = sm[cur] + 4608;

    // K A-frags: A[m=key][k=hd]: lane l16 = key (per subtile ks), contiguous hd
    bf16x8 kf[4][2];
#pragma unroll
    for (int ks = 0; ks < 4; ++ks)
#pragma unroll
      for (int st = 0; st < 2; ++st)
        kf[ks][st] = *(const bf16x8*)(Ks + (ks * 16 + l16) * 72 + st * 32 + quad * 8);

    // V B-frags under sigma: two b64 chunks (keys st*32+quad*4+{0..3}, +16)
    bf16x8 vf[4][2];
#pragma unroll
    for (int os = 0; os < 4; ++os)
#pragma unroll
      for (int st = 0; st < 2; ++st) {
        const unsigned short* rb = Vts + (os * 16 + l16) * 72 + st * 32 + quad * 4;
        bf16x4 a = *(const bf16x4*)rb;
        bf16x4 b2 = *(const bf16x4*)(rb + 16);
        vf[os][st] = __builtin_shufflevector(a, b2, 0, 1, 2, 3, 4, 5, 6, 7);
      }

#pragma unroll
    for (int qt = 0; qt < 4; ++qt) {
      // S^T tiles: rows = keys (quad*4+r), cols = qrows (l16)
      f32x4 sc[4];
#pragma unroll
      for (int ks = 0; ks < 4; ++ks) {
        f32x4 a = {0.f, 0.f, 0.f, 0.f};
        a = MFMA16(kf[ks][0], qf[qt][0], a);
        a = MFMA16(kf[ks][1], qf[qt][1], a);
        sc[ks] = a;
      }
      // exp2 -> P A-frags in-register; per-lane l partials (all for qrow l16)
      bf16x8 pf[2];
      float ls = 0.f;
#pragma unroll
      for (int ks = 0; ks < 4; ++ks)
#pragma unroll
        for (int r = 0; r < 4; ++r) {
          float p = __builtin_amdgcn_exp2f(sc[ks][r]);
          ls += p;
          pf[ks >> 1][(ks & 1) * 4 + r] = (__bf16)p;
        }
      lacc[qt] += ls;
#pragma unroll
      for (int st = 0; st < 2; ++st)
#pragma unroll
        for (int os = 0; os < 4; ++os)
          o[qt][os] = MFMA16(pf[st], vf[os][st], o[qt][os]);
    }

    if (more) {
      unsigned short* sn = sm[cur ^ 1];
      *(u32x4*)(sn + sKo) = pk0; *(u32x4*)(sn + sKo1) = pk1;
      *(u32x4*)(sn + 4608 + sKo) = pv0; *(u32x4*)(sn + 4608 + sKo1) = pv1;
    }
    __syncthreads();
  }

  // finalize: reduce l across quads (lane's l16 = qrow), redistribute to
  // C-layout rows (quad*4+r), normalize, store.
  const int b = bh >> 4, h = bh & 15;
#pragma unroll
  for (int qt = 0; qt < 4; ++qt) {
    float l = lacc[qt];
    l += __shfl_xor(l, 16, 64);
    l += __shfl_xor(l, 32, 64);
#pragma unroll
    for (int r = 0; r < 4; ++r) {
      float lr = __shfl(l, quad * 4 + r, 16);
      float inv = 1.0f / lr;
      int s = q0 + qt * 16 + quad * 4 + r;
#pragma unroll
      for (int os = 0; os < 4; ++os)
        ctx[((size_t)(b * 2048 + s)) * 1024 + h * 64 + os * 16 + l16] = f2bf(o[qt][os][r] * inv);
    }
  }
}

// ---------------------------------------------------------------- launch
extern "C" void kernel_launch(void* const* d_in, const int* in_sizes, int n_in,
                              void* d_out, int out_size, void* d_ws, size_t ws_size,
                              hipStream_t stream) {
  const float* x  = (const float*)d_in[0];
  const float* Wq = (const float*)d_in[1];
  const float* bq = (const float*)d_in[2];
  const float* Wk = (const float*)d_in[3];
  const float* bk = (const float*)d_in[4];
  const float* Wv = (const float*)d_in[5];
  const float* bv = (const float*)d_in[6];
  const float* Wo = (const float*)d_in[7];
  const float* bo = (const float*)d_in[8];

  unsigned short* ws = (unsigned short*)d_ws;
  unsigned short* xb    = ws;                    // 8388608 (aliased by VtG later)
  unsigned short* Wtall = ws + 8388608;          // 4*1048576 (Wq^T|Wk^T|Wv^T|Wo^T)
  unsigned short* Wot   = Wtall + 3145728;
  unsigned short* Qb    = Wtall + 4194304;       // 8388608  [bh][s][hd], pre-scaled
  unsigned short* Kb    = Qb + 8388608;          // 8388608
  unsigned short* Vb    = Kb + 8388608;          // 8388608
  unsigned short* VtG   = xb;                    // alias: xb dead after QKV GEMM
  unsigned short* Cb    = Vb;                    // alias: Vb dead after transpose_v

  cast_x_kernel<<<8192, 256, 0, stream>>>(x, xb, 2097152);
  transpose_cast4<<<dim3(32, 32, 4), dim3(32, 8), 0, stream>>>(Wq, Wk, Wv, Wo, Wtall);

  gemm256_qkv<<<dim3(384), 512, 0, stream>>>(xb, Wtall, bq, bk, bv, Qb);
  transpose_v<<<dim3(32, 64), 256, 0, stream>>>(Vb, VtG);
  attn_kernel<<<dim3(512), 256, 0, stream>>>(Qb, Kb, VtG, Cb);
  gemm128<0><<<dim3(512), 256, 0, stream>>>(Cb, Wot, bo, nullptr, nullptr, d_out);
}

// Round 8
// 292.547 us; speedup vs baseline: 1.0441x; 1.0441x over previous
//
#include <hip/hip_runtime.h>
#include <stdint.h>

// B=4, S=2048, D=1024, H=16, Hd=64, M=8192.
// Pipeline: cast x -> bf16; merged W^T casts; QKV GEMM (256^2, 8-phase
// counted-vmcnt schedule, fragment-major LDS); V transpose; flash attn
// (S^T = K@Q^T key-permutation trick); O-projection GEMM (fp32 out).
// R4: 256^2 counted-vmcnt QKV 23% MfmaUtil (8-way LDS conflicts).
// R5: fragment-major LDS -> conflicts 0; 80.8us; still 2-phase-like lockstep.
// R6/R7: 64KB 2-buf depth-1: occupancy did NOT rise (acc[8][4]=128 AGPR in
//     unified file -> ~212 regs -> 2 waves/SIMD cap, LDS never binding);
//     lost prefetch slack -> 94.6us. Lesson: 256^2 tile cannot gain TLP;
//     the lever is the schedule (guide: 2-phase caps ~600TF; 8-phase +28-73%).
// R8: m201-style 8-phase port: BK=64, 16 K-tiles, 2x64KB LDS dbuf,
//     4 phases/tile {ds_read frags || stage quarter U(t+1) -> bar ->
//     lgkmcnt(0) -> setprio(1) 16 MFMA setprio(0) -> bar}; counted vmcnt(4)
//     before the barrier at phases 2 and 4 (never 0 in steady state).

typedef float f32x4 __attribute__((ext_vector_type(4)));
typedef __bf16 bf16x4 __attribute__((ext_vector_type(4)));
typedef __bf16 bf16x8 __attribute__((ext_vector_type(8)));
typedef uint32_t u32x4 __attribute__((ext_vector_type(4)));

#define MFMA16(a, b, c) __builtin_amdgcn_mfma_f32_16x16x32_bf16((a), (b), (c), 0, 0, 0)

// Q pre-scale: log2(e)/8 so attn does p = exp2(Q'.K) = e^{QK/8} (unnormalized)
#define QSCALE 0.1803368801111204f

__device__ __forceinline__ unsigned short f2bf(float f) {
  union { float f; uint32_t u; } c; c.f = f;
  uint32_t u = c.u;
  return (unsigned short)((u + 0x7fffu + ((u >> 16) & 1u)) >> 16);  // RNE
}

// ---------------------------------------------------------------- casts
__global__ __launch_bounds__(256) void cast_x_kernel(const float* __restrict__ in,
                                                     unsigned short* __restrict__ out,
                                                     int n4) {
  int i = blockIdx.x * 256 + threadIdx.x;
  if (i >= n4) return;
  float4 v = ((const float4*)in)[i];
  ushort4 o;
  o.x = f2bf(v.x); o.y = f2bf(v.y); o.z = f2bf(v.z); o.w = f2bf(v.w);
  ((ushort4*)out)[i] = o;
}

// 4 weights [k][n] fp32 -> Wt [n][k] bf16, z selects matrix; dst contiguous.
__global__ __launch_bounds__(256) void transpose_cast4(const float* __restrict__ W0,
                                                       const float* __restrict__ W1,
                                                       const float* __restrict__ W2,
                                                       const float* __restrict__ W3,
                                                       unsigned short* __restrict__ Wt) {
  __shared__ float tile[32][33];
  const int z = blockIdx.z;
  const float* W = (z == 0) ? W0 : (z == 1) ? W1 : (z == 2) ? W2 : W3;
  unsigned short* dst = Wt + (size_t)z * 1048576;
  int k0 = blockIdx.x * 32, n0 = blockIdx.y * 32;
  int tx = threadIdx.x, ty = threadIdx.y;
#pragma unroll
  for (int i = 0; i < 32; i += 8)
    tile[ty + i][tx] = W[(size_t)(k0 + ty + i) * 1024 + n0 + tx];
  __syncthreads();
#pragma unroll
  for (int i = 0; i < 32; i += 8)
    dst[(size_t)(n0 + ty + i) * 1024 + k0 + tx] = f2bf(tile[tx][ty + i]);
}

// ---------------------------------------------------------------- QKV GEMM 256^2, 8-phase
// A [8192][1024] bf16, Bt [3072][1024] bf16. out = QKV bf16 base (3 x 8388608),
// scatter to [b,h,s,hd]; Q (mb==0) scaled by QSCALE.
// BK=64, 16 K-tiles, 2 x 64KB LDS buffers. Per buffer (fragment-major, R5):
//   U1 A[k 0..32): blocks msub*1KB, chunk lane*16B = A[msub*16+l16][quad*8..+8)
//   U2 B[k 0..32)  (+16KB)   U3 A[k 32..64) (+32KB)   U4 B[k 32..64) (+48KB)
// Tile t reads buf t&1; tile t+1 staged into buf^1, one U per phase.
// vmcnt(4) before the phase-2 barrier (U3,U4 of t landed for phases 3-4) and
// before the phase-4 barrier (U1,U2 of t+1 landed for next phases 1-2);
// per-wave vmcnt + barrier => block-wide guarantee. Never 0 in steady state.
__global__ __launch_bounds__(512) void gemm256_qkv(const unsigned short* __restrict__ A,
                                                   const unsigned short* __restrict__ Bt,
                                                   const float* __restrict__ b0,
                                                   const float* __restrict__ b1,
                                                   const float* __restrict__ b2,
                                                   unsigned short* __restrict__ out) {
  __shared__ unsigned short sm[2 * 32768];  // 128 KB
  auto lds3 = (__attribute__((address_space(3))) char*)sm;

  const int tid = threadIdx.x;
  const int wave = tid >> 6, lane = tid & 63, quad = lane >> 4, l16 = lane & 15;
  const int wm = wave >> 2, wn = wave & 3;

  // XCD-chunked decode: XCD owns 4 row-panels (A 2MB L2-resident), bx-major.
  const int id = blockIdx.x;
  const int nid = id >> 3;
  const int by = (id & 7) * 4 + (nid & 3);
  const int bx = nid >> 2;
  const int bm = by * 256, bn = bx * 256;

  // staging thread-base pointers (fragment-major sources)
  const unsigned short* gA = A + (size_t)(bm + l16) * 1024 + quad * 8;
  const unsigned short* gB = Bt + (size_t)(bn + l16) * 1024 + quad * 8;

#define GLDS(gp, lo)                                                         \
  __builtin_amdgcn_global_load_lds(                                          \
      (const __attribute__((address_space(1))) void*)(gp),                   \
      (__attribute__((address_space(3))) void*)(lds3 + (lo)), 16, 0, 0)

// stage one 16KB quarter: A cols [koff+kk*32 .. +32), blocks bi = wave, wave+8
#define STAGE_A(bb, kk, koff)                                                \
  do {                                                                       \
    GLDS(gA + (size_t)(wave * 16) * 1024 + (koff) + (kk) * 32,               \
         (bb) * 65536 + (kk) * 32768 + wave * 1024);                         \
    GLDS(gA + (size_t)((wave + 8) * 16) * 1024 + (koff) + (kk) * 32,         \
         (bb) * 65536 + (kk) * 32768 + (wave + 8) * 1024);                   \
  } while (0)
#define STAGE_B(bb, kk, koff)                                                \
  do {                                                                       \
    GLDS(gB + (size_t)(wave * 16) * 1024 + (koff) + (kk) * 32,               \
         (bb) * 65536 + 16384 + (kk) * 32768 + wave * 1024);                 \
    GLDS(gB + (size_t)((wave + 8) * 16) * 1024 + (koff) + (kk) * 32,         \
         (bb) * 65536 + 16384 + (kk) * 32768 + (wave + 8) * 1024);           \
  } while (0)

  f32x4 acc[8][4] = {};

  // prologue: tile 0 fully into buffer 0
  STAGE_A(0, 0, 0); STAGE_B(0, 0, 0); STAGE_A(0, 1, 0); STAGE_B(0, 1, 0);
  asm volatile("s_waitcnt vmcnt(0)" ::: "memory");
  __builtin_amdgcn_s_barrier();

  for (int t = 0; t < 16; ++t) {
    const int buf = t & 1, nbuf = buf ^ 1;
    const int k1 = (t + 1) * 64;
    const unsigned short* base = sm + buf * 32768;
    const bool more = t < 15;

    bf16x8 af[4], bfv[4];

    // ---------- phase 1: read B(k-lo) + A(m-lo,k-lo); stage U1(t+1)
#pragma unroll
    for (int n = 0; n < 4; ++n)
      bfv[n] = *(const bf16x8*)(base + 8192 + (wn * 4 + n) * 512 + lane * 8);
#pragma unroll
    for (int i = 0; i < 4; ++i)
      af[i] = *(const bf16x8*)(base + (wm * 8 + i) * 512 + lane * 8);
    if (more) STAGE_A(nbuf, 0, k1);
    __builtin_amdgcn_s_barrier();
    asm volatile("s_waitcnt lgkmcnt(0)" ::: "memory");
    __builtin_amdgcn_s_setprio(1);
#pragma unroll
    for (int i = 0; i < 4; ++i)
#pragma unroll
      for (int n = 0; n < 4; ++n)
        acc[i][n] = MFMA16(af[i], bfv[n], acc[i][n]);
    __builtin_amdgcn_s_setprio(0);
    __builtin_amdgcn_s_barrier();

    // ---------- phase 2: read A(m-hi,k-lo); stage U2(t+1); gate U3,U4(t)
#pragma unroll
    for (int i = 0; i < 4; ++i)
      af[i] = *(const bf16x8*)(base + (wm * 8 + 4 + i) * 512 + lane * 8);
    if (more) STAGE_B(nbuf, 0, k1);
    __builtin_amdgcn_s_barrier();
    asm volatile("s_waitcnt lgkmcnt(0)" ::: "memory");
    __builtin_amdgcn_s_setprio(1);
#pragma unroll
    for (int i = 0; i < 4; ++i)
#pragma unroll
      for (int n = 0; n < 4; ++n)
        acc[4 + i][n] = MFMA16(af[i], bfv[n], acc[4 + i][n]);
    __builtin_amdgcn_s_setprio(0);
    if (more) asm volatile("s_waitcnt vmcnt(4)" ::: "memory");
    else      asm volatile("s_waitcnt vmcnt(0)" ::: "memory");
    __builtin_amdgcn_s_barrier();

    // ---------- phase 3: read B(k-hi) + A(m-lo,k-hi); stage U3(t+1)
#pragma unroll
    for (int n = 0; n < 4; ++n)
      bfv[n] = *(const bf16x8*)(base + 24576 + (wn * 4 + n) * 512 + lane * 8);
#pragma unroll
    for (int i = 0; i < 4; ++i)
      af[i] = *(const bf16x8*)(base + 16384 + (wm * 8 + i) * 512 + lane * 8);
    if (more) STAGE_A(nbuf, 1, k1);
    __builtin_amdgcn_s_barrier();
    asm volatile("s_waitcnt lgkmcnt(0)" ::: "memory");
    __builtin_amdgcn_s_setprio(1);
#pragma unroll
    for (int i = 0; i < 4; ++i)
#pragma unroll
      for (int n = 0; n < 4; ++n)
        acc[i][n] = MFMA16(af[i], bfv[n], acc[i][n]);
    __builtin_amdgcn_s_setprio(0);
    __builtin_amdgcn_s_barrier();

    // ---------- phase 4: read A(m-hi,k-hi); stage U4(t+1); gate U1,U2(t+1)
#pragma unroll
    for (int i = 0; i < 4; ++i)
      af[i] = *(const bf16x8*)(base + 16384 + (wm * 8 + 4 + i) * 512 + lane * 8);
    if (more) STAGE_B(nbuf, 1, k1);
    __builtin_amdgcn_s_barrier();
    asm volatile("s_waitcnt lgkmcnt(0)" ::: "memory");
    __builtin_amdgcn_s_setprio(1);
#pragma unroll
    for (int i = 0; i < 4; ++i)
#pragma unroll
      for (int n = 0; n < 4; ++n)
        acc[4 + i][n] = MFMA16(af[i], bfv[n], acc[4 + i][n]);
    __builtin_amdgcn_s_setprio(0);
    if (more) asm volatile("s_waitcnt vmcnt(4)" ::: "memory");
    else      asm volatile("s_waitcnt vmcnt(0)" ::: "memory");
    __builtin_amdgcn_s_barrier();
  }
#undef STAGE_A
#undef STAGE_B
#undef GLDS

  // epilogue: C/D layout col=lane&15, row=quad*4+reg; scatter to [b,h,s,hd]
  const int mb = bn >> 10;  // block (256 cols) never straddles: 1024 % 256 == 0
  const float* bias = (mb == 0) ? b0 : (mb == 1 ? b1 : b2);
  const float scale = (mb == 0) ? QSCALE : 1.0f;
  unsigned short* oq = out + (size_t)mb * 8388608u;

#pragma unroll
  for (int i = 0; i < 8; ++i) {
    const int row0 = bm + wm * 128 + i * 16 + quad * 4;
#pragma unroll
    for (int n = 0; n < 4; ++n) {
      const int col = bn + wn * 64 + n * 16 + l16;
      const int cl = col & 1023;
      const float bv = bias[cl];
      const int h = cl >> 6, hd = cl & 63;
#pragma unroll
      for (int r = 0; r < 4; ++r) {
        const int rr = row0 + r;
        const int b = rr >> 11, s = rr & 2047;
        float v = (acc[i][n][r] + bv) * scale;
        oq[((size_t)(b * 16 + h) * 2048 + s) * 64 + hd] = f2bf(v);
      }
    }
  }
}

// ---------------------------------------------------------------- O-proj GEMM
// out fp32 [8192][1024], bias b0. grid 512 flat, XCD-chunked decode.
// Fragment-major LDS (same scheme as gemm256): zero-conflict frag reads.
template <int MODE>
__global__ __launch_bounds__(256) void gemm128(const unsigned short* __restrict__ A,
                                               const unsigned short* __restrict__ Bt,
                                               const float* __restrict__ b0,
                                               const float* __restrict__ b1,
                                               const float* __restrict__ b2,
                                               void* __restrict__ out) {
  constexpr int Kd = 1024;
  __shared__ unsigned short sm[8192];  // A 8KB | B 8KB
  auto lds3 = (__attribute__((address_space(3))) char*)sm;

  const int tid = threadIdx.x;
  const int wave = tid >> 6, lane = tid & 63, quad = lane >> 4, l16 = lane & 15;
  const int wm = wave >> 1, wn = wave & 1;

  const int id = blockIdx.x;
  const int nid = id >> 3;
  const int by = (id & 7) * 8 + (nid & 7);
  const int bx = nid >> 3;
  const int bm = by * 128, bn = bx * 128;

  // staging: wave stages msub {wave, wave+4} of A and B (8 subtiles each)
  const unsigned short* gA0 = A + (size_t)(bm + wave * 16 + l16) * Kd + quad * 8;
  const unsigned short* gA1 = gA0 + (size_t)64 * Kd;
  const unsigned short* gB0 = Bt + (size_t)(bn + wave * 16 + l16) * Kd + quad * 8;
  const unsigned short* gB1 = gB0 + (size_t)64 * Kd;
  const int ldw = wave * 1024;

  f32x4 acc[4][4] = {};

  for (int k0 = 0; k0 < Kd; k0 += 32) {
    __builtin_amdgcn_global_load_lds(
        (const __attribute__((address_space(1))) void*)(gA0 + k0),
        (__attribute__((address_space(3))) void*)(lds3 + ldw), 16, 0, 0);
    __builtin_amdgcn_global_load_lds(
        (const __attribute__((address_space(1))) void*)(gA1 + k0),
        (__attribute__((address_space(3))) void*)(lds3 + 4096 + ldw), 16, 0, 0);
    __builtin_amdgcn_global_load_lds(
        (const __attribute__((address_space(1))) void*)(gB0 + k0),
        (__attribute__((address_space(3))) void*)(lds3 + 8192 + ldw), 16, 0, 0);
    __builtin_amdgcn_global_load_lds(
        (const __attribute__((address_space(1))) void*)(gB1 + k0),
        (__attribute__((address_space(3))) void*)(lds3 + 12288 + ldw), 16, 0, 0);
    __syncthreads();

    bf16x8 af[4], bfv[4];
#pragma unroll
    for (int i = 0; i < 4; ++i)
      af[i] = *(const bf16x8*)(sm + ((wm * 4 + i) << 9) + (lane << 3));
#pragma unroll
    for (int n = 0; n < 4; ++n)
      bfv[n] = *(const bf16x8*)(sm + 4096 + ((wn * 4 + n) << 9) + (lane << 3));
#pragma unroll
    for (int i = 0; i < 4; ++i)
#pragma unroll
      for (int n = 0; n < 4; ++n)
        acc[i][n] = MFMA16(af[i], bfv[n], acc[i][n]);
    __syncthreads();
  }

  // epilogue: C/D layout col=lane&15, row=quad*4+reg
  const float* bias = b0;
#pragma unroll
  for (int i = 0; i < 4; ++i) {
    const int row0 = bm + wm * 64 + i * 16 + quad * 4;
#pragma unroll
    for (int n = 0; n < 4; ++n) {
      const int col = bn + wn * 64 + n * 16 + l16;
      const float bv = bias[col & 1023];
#pragma unroll
      for (int r = 0; r < 4; ++r) {
        float v = acc[i][n][r] + bv;
        ((float*)out)[(size_t)(row0 + r) * 1024 + col] = v;
      }
    }
  }
}

// ---------------------------------------------------------------- V transpose
// Vb [bh][s][64] bf16 -> VtG [bh][64][2048] bf16.
__global__ __launch_bounds__(256) void transpose_v(const unsigned short* __restrict__ Vb,
                                                   unsigned short* __restrict__ VtG) {
  __shared__ uint32_t t32[64][33];
  const int bh = blockIdx.y, s0 = blockIdx.x * 64;
  const int tid = threadIdx.x;
  const size_t hbase = (size_t)bh * 131072;
#pragma unroll
  for (int it = 0; it < 2; ++it) {
    int c = tid + it * 256;
    int sr = c >> 3, o4 = (c & 7) * 4;
    u32x4 v = *(const u32x4*)(Vb + hbase + (size_t)(s0 + sr) * 64 + o4 * 2);
    t32[sr][o4] = v[0]; t32[sr][o4 + 1] = v[1];
    t32[sr][o4 + 2] = v[2]; t32[sr][o4 + 3] = v[3];
  }
  __syncthreads();
#pragma unroll
  for (int it = 0; it < 2; ++it) {
    int c = tid + it * 256;
    int hd = c >> 3, so = (c & 7) * 8;
    int hc = hd >> 1, sh = (hd & 1) * 16;
    uint32_t w[4];
#pragma unroll
    for (int j = 0; j < 4; ++j) {
      uint32_t lo = t32[so + 2 * j][hc], hi = t32[so + 2 * j + 1][hc];
      w[j] = ((lo >> sh) & 0xffffu) | (((hi >> sh) & 0xffffu) << 16);
    }
    *(u32x4*)(VtG + hbase + (size_t)hd * 2048 + s0 + so) = *(u32x4*)w;
  }
}

// ---------------------------------------------------------------- flash attention
// Q pre-scaled. 512 flat blocks; block = (b,h) x 256 q-rows; wave = 64 q-rows
// (4 subtiles). XCD-grouped decode: bh = (id&7)*8 + ((id>>3)>>3) so all 8
// q-blocks of a head (and 8 whole heads) land on one XCD -> K/Vt L2-resident
// (proven R2/R3: FETCH 139 -> 25.7 MB). No setprio: lockstep loop (m190/R3).
// S^T = K(A) @ Q^T(B): C-layout puts col=l16=qrow, so each lane's 16 exp2'd
// scores (keys quad*4+r per subtile) form PV A-frags directly under the key
// permutation sigma(q*8+j) = st*32 + (j>>2)*16 + q*4 + (j&3); V B-frags use
// the same sigma (two contiguous b64 chunks from the Vt tile). No P in LDS.
__global__ __launch_bounds__(256, 2) void attn_kernel(const unsigned short* __restrict__ Q,
                                                      const unsigned short* __restrict__ K,
                                                      const unsigned short* __restrict__ Vt,
                                                      unsigned short* __restrict__ ctx) {
  const int tid = threadIdx.x;
  const int wave = tid >> 6, lane = tid & 63, quad = lane >> 4, l16 = lane & 15;

  const int id = blockIdx.x;
  const int bh = (id & 7) * 8 + ((id >> 3) >> 3);  // 8 heads per XCD
  const int qx = (id >> 3) & 7;

  // stride 72 ushorts = 36 dwords == 4 mod 32 -> conflict-free-ish frag reads
  // double buffer: [buf][Ks 64*72 | Vts 64*72]
  __shared__ unsigned short sm[2][2 * 64 * 72];

  const size_t hb = (size_t)bh * 131072;
  const int q0 = qx * 256 + wave * 64;

  // Q B-frags: B[k=hd][n=qrow]: lane l16 = qrow, k = quad*8+j (+32*st)
  bf16x8 qf[4][2];
#pragma unroll
  for (int qt = 0; qt < 4; ++qt)
#pragma unroll
    for (int st = 0; st < 2; ++st)
      qf[qt][st] = *(const bf16x8*)(Q + hb + (size_t)(q0 + qt * 16 + l16) * 64 + st * 32 + quad * 8);

  f32x4 o[4][4] = {};
  float lacc[4] = {0.f, 0.f, 0.f, 0.f};

  // staging: 4 x 16B chunks/thread (2 K rows-of-keys + 2 Vt rows-of-hd)
  const int c0 = tid, c1 = tid + 256;
  const unsigned short* gK0 = K + hb + (size_t)(c0 >> 3) * 64 + (c0 & 7) * 8;
  const unsigned short* gK1 = K + hb + (size_t)(c1 >> 3) * 64 + (c1 & 7) * 8;
  const unsigned short* gV0 = Vt + hb + (size_t)(c0 >> 3) * 2048 + (c0 & 7) * 8;
  const unsigned short* gV1 = Vt + hb + (size_t)(c1 >> 3) * 2048 + (c1 & 7) * 8;
  const int sKo = (c0 >> 3) * 72 + (c0 & 7) * 8;
  const int sKo1 = (c1 >> 3) * 72 + (c1 & 7) * 8;

  u32x4 pk0 = *(const u32x4*)gK0, pk1 = *(const u32x4*)gK1;
  u32x4 pv0 = *(const u32x4*)gV0, pv1 = *(const u32x4*)gV1;
  {
    unsigned short* s0b = sm[0];
    *(u32x4*)(s0b + sKo) = pk0; *(u32x4*)(s0b + sKo1) = pk1;
    *(u32x4*)(s0b + 4608 + sKo) = pv0; *(u32x4*)(s0b + 4608 + sKo1) = pv1;
  }
  __syncthreads();

  for (int kb = 0; kb < 2048; kb += 64) {
    const int cur = (kb >> 6) & 1;
    const bool more = (kb + 64) < 2048;
    if (more) {
      pk0 = *(const u32x4*)(gK0 + (size_t)(kb + 64) * 64);
      pk1 = *(const u32x4*)(gK1 + (size_t)(kb + 64) * 64);
      pv0 = *(const u32x4*)(gV0 + kb + 64);
      pv1 = *(const u32x4*)(gV1 + kb + 64);
    }
    const unsigned short* Ks = sm[cur];
    const unsigned short* Vts = sm[cur] + 4608;

    // K A-frags: A[m=key][k=hd]: lane l16 = key (per subtile ks), contiguous hd
    bf16x8 kf[4][2];
#pragma unroll
    for (int ks = 0; ks < 4; ++ks)
#pragma unroll
      for (int st = 0; st < 2; ++st)
        kf[ks][st] = *(const bf16x8*)(Ks + (ks * 16 + l16) * 72 + st * 32 + quad * 8);

    // V B-frags under sigma: two b64 chunks (keys st*32+quad*4+{0..3}, +16)
    bf16x8 vf[4][2];
#pragma unroll
    for (int os = 0; os < 4; ++os)
#pragma unroll
      for (int st = 0; st < 2; ++st) {
        const unsigned short* rb = Vts + (os * 16 + l16) * 72 + st * 32 + quad * 4;
        bf16x4 a = *(const bf16x4*)rb;
        bf16x4 b2 = *(const bf16x4*)(rb + 16);
        vf[os][st] = __builtin_shufflevector(a, b2, 0, 1, 2, 3, 4, 5, 6, 7);
      }

#pragma unroll
    for (int qt = 0; qt < 4; ++qt) {
      // S^T tiles: rows = keys (quad*4+r), cols = qrows (l16)
      f32x4 sc[4];
#pragma unroll
      for (int ks = 0; ks < 4; ++ks) {
        f32x4 a = {0.f, 0.f, 0.f, 0.f};
        a = MFMA16(kf[ks][0], qf[qt][0], a);
        a = MFMA16(kf[ks][1], qf[qt][1], a);
        sc[ks] = a;
      }
      // exp2 -> P A-frags in-register; per-lane l partials (all for qrow l16)
      bf16x8 pf[2];
      float ls = 0.f;
#pragma unroll
      for (int ks = 0; ks < 4; ++ks)
#pragma unroll
        for (int r = 0; r < 4; ++r) {
          float p = __builtin_amdgcn_exp2f(sc[ks][r]);
          ls += p;
          pf[ks >> 1][(ks & 1) * 4 + r] = (__bf16)p;
        }
      lacc[qt] += ls;
#pragma unroll
      for (int st = 0; st < 2; ++st)
#pragma unroll
        for (int os = 0; os < 4; ++os)
          o[qt][os] = MFMA16(pf[st], vf[os][st], o[qt][os]);
    }

    if (more) {
      unsigned short* sn = sm[cur ^ 1];
      *(u32x4*)(sn + sKo) = pk0; *(u32x4*)(sn + sKo1) = pk1;
      *(u32x4*)(sn + 4608 + sKo) = pv0; *(u32x4*)(sn + 4608 + sKo1) = pv1;
    }
    __syncthreads();
  }

  // finalize: reduce l across quads (lane's l16 = qrow), redistribute to
  // C-layout rows (quad*4+r), normalize, store.
  const int b = bh >> 4, h = bh & 15;
#pragma unroll
  for (int qt = 0; qt < 4; ++qt) {
    float l = lacc[qt];
    l += __shfl_xor(l, 16, 64);
    l += __shfl_xor(l, 32, 64);
#pragma unroll
    for (int r = 0; r < 4; ++r) {
      float lr = __shfl(l, quad * 4 + r, 16);
      float inv = 1.0f / lr;
      int s = q0 + qt * 16 + quad * 4 + r;
#pragma unroll
      for (int os = 0; os < 4; ++os)
        ctx[((size_t)(b * 2048 + s)) * 1024 + h * 64 + os * 16 + l16] = f2bf(o[qt][os][r] * inv);
    }
  }
}

// ---------------------------------------------------------------- launch
extern "C" void kernel_launch(void* const* d_in, const int* in_sizes, int n_in,
                              void* d_out, int out_size, void* d_ws, size_t ws_size,
                              hipStream_t stream) {
  const float* x  = (const float*)d_in[0];
  const float* Wq = (const float*)d_in[1];
  const float* bq = (const float*)d_in[2];
  const float* Wk = (const float*)d_in[3];
  const float* bk = (const float*)d_in[4];
  const float* Wv = (const float*)d_in[5];
  const float* bv = (const float*)d_in[6];
  const float* Wo = (const float*)d_in[7];
  const float* bo = (const float*)d_in[8];

  unsigned short* ws = (unsigned short*)d_ws;
  unsigned short* xb    = ws;                    // 8388608 (aliased by VtG later)
  unsigned short* Wtall = ws + 8388608;          // 4*1048576 (Wq^T|Wk^T|Wv^T|Wo^T)
  unsigned short* Wot   = Wtall + 3145728;
  unsigned short* Qb    = Wtall + 4194304;       // 8388608  [bh][s][hd], pre-scaled
  unsigned short* Kb    = Qb + 8388608;          // 8388608
  unsigned short* Vb    = Kb + 8388608;          // 8388608
  unsigned short* VtG   = xb;                    // alias: xb dead after QKV GEMM
  unsigned short* Cb    = Vb;                    // alias: Vb dead after transpose_v

  cast_x_kernel<<<8192, 256, 0, stream>>>(x, xb, 2097152);
  transpose_cast4<<<dim3(32, 32, 4), dim3(32, 8), 0, stream>>>(Wq, Wk, Wv, Wo, Wtall);

  gemm256_qkv<<<dim3(384), 512, 0, stream>>>(xb, Wtall, bq, bk, bv, Qb);
  transpose_v<<<dim3(32, 64), 256, 0, stream>>>(Vb, VtG);
  attn_kernel<<<dim3(512), 256, 0, stream>>>(Qb, Kb, VtG, Cb);
  gemm128<0><<<dim3(512), 256, 0, stream>>>(Cb, Wot, bo, nullptr, nullptr, d_out);
}

// Round 10
// 268.623 us; speedup vs baseline: 1.1371x; 1.0891x over previous
//
#include <hip/hip_runtime.h>
#include <stdint.h>

// B=4, S=2048, D=1024, H=16, Hd=64, M=8192.
// Pipeline: cast x -> bf16; merged W^T casts; merged QKV GEMM (128^2 tile,
// XCD-chunked; Q pre-scaled by log2e/8; V written TRANSPOSED [bh][hd][s]
// directly from the epilogue -> no transpose_v kernel); flash attn
// (S^T = K@Q^T key-permutation trick); O-projection GEMM (fp32 out).
// Ledger: R2 XCD decode cuts attn FETCH 139->24.6MB. R3 setprio hurts
// lockstep attn (m190); GEMM XCD swizzle helps; best total 272.9.
// R4-R8: 256^2 QKV at 3 schedules (counted-vmcnt depth-2/1, full 8-phase)
// all ~80-95us @ ~24% MfmaUtil: K=1024 (16 tiles) + 384-block grid (1.5
// dispatch rounds, x1.33 quantization) pin the 256^2 tile; fragment-major
// O-proj rewrite suspected -17us (R4 274.8 vs R5/R8 291+).
// R9: revert both GEMMs to proven R3/R4 row-major 128^2 (1536/512 blocks,
// 3 blocks/CU TLP); NEW: fuse V-transpose into QKV epilogue (mb==2 writes
// Vt[bh][hd][s] via 8B ushort4 stores: 4 consecutive s per thread) ->
// transpose_v kernel deleted (-67MB traffic, -1 dispatch). Buffers: VtG
// takes Vb slot; attn out -> xb (dead after QKV).
// (R9 bench: container failed twice = infra; resubmitted unchanged.)

typedef float f32x4 __attribute__((ext_vector_type(4)));
typedef __bf16 bf16x4 __attribute__((ext_vector_type(4)));
typedef __bf16 bf16x8 __attribute__((ext_vector_type(8)));
typedef uint32_t u32x4 __attribute__((ext_vector_type(4)));

#define MFMA16(a, b, c) __builtin_amdgcn_mfma_f32_16x16x32_bf16((a), (b), (c), 0, 0, 0)

// Q pre-scale: log2(e)/8 so attn does p = exp2(Q'.K) = e^{QK/8} (unnormalized)
#define QSCALE 0.1803368801111204f

__device__ __forceinline__ unsigned short f2bf(float f) {
  union { float f; uint32_t u; } c; c.f = f;
  uint32_t u = c.u;
  return (unsigned short)((u + 0x7fffu + ((u >> 16) & 1u)) >> 16);  // RNE
}

// ---------------------------------------------------------------- casts
__global__ __launch_bounds__(256) void cast_x_kernel(const float* __restrict__ in,
                                                     unsigned short* __restrict__ out,
                                                     int n4) {
  int i = blockIdx.x * 256 + threadIdx.x;
  if (i >= n4) return;
  float4 v = ((const float4*)in)[i];
  ushort4 o;
  o.x = f2bf(v.x); o.y = f2bf(v.y); o.z = f2bf(v.z); o.w = f2bf(v.w);
  ((ushort4*)out)[i] = o;
}

// 4 weights [k][n] fp32 -> Wt [n][k] bf16, z selects matrix; dst contiguous.
__global__ __launch_bounds__(256) void transpose_cast4(const float* __restrict__ W0,
                                                       const float* __restrict__ W1,
                                                       const float* __restrict__ W2,
                                                       const float* __restrict__ W3,
                                                       unsigned short* __restrict__ Wt) {
  __shared__ float tile[32][33];
  const int z = blockIdx.z;
  const float* W = (z == 0) ? W0 : (z == 1) ? W1 : (z == 2) ? W2 : W3;
  unsigned short* dst = Wt + (size_t)z * 1048576;
  int k0 = blockIdx.x * 32, n0 = blockIdx.y * 32;
  int tx = threadIdx.x, ty = threadIdx.y;
#pragma unroll
  for (int i = 0; i < 32; i += 8)
    tile[ty + i][tx] = W[(size_t)(k0 + ty + i) * 1024 + n0 + tx];
  __syncthreads();
#pragma unroll
  for (int i = 0; i < 32; i += 8)
    dst[(size_t)(n0 + ty + i) * 1024 + k0 + tx] = f2bf(tile[tx][ty + i]);
}

// ---------------------------------------------------------------- GEMM 128^2 (R3-proven)
// MODE 0: O-proj. out fp32 [8192][1024], bias b0. grid 512 flat.
// MODE 1: merged QKV. Bt = [3072][1024], out = QKV bf16 base (Q,K scatter to
//         [b,h,s,hd]; Q scaled by QSCALE); mb==2 (V) written TRANSPOSED to
//         vtg[bh][hd][s] as 8B ushort4 (4 consecutive s). grid 1536 flat.
// XCD-chunked decode: XCD x owns by in [8x, 8x+8); bx-major, by-inner.
template <int MODE>
__global__ __launch_bounds__(256) void gemm128(const unsigned short* __restrict__ A,
                                               const unsigned short* __restrict__ Bt,
                                               const float* __restrict__ b0,
                                               const float* __restrict__ b1,
                                               const float* __restrict__ b2,
                                               void* __restrict__ out,
                                               unsigned short* __restrict__ vtg) {
  constexpr int Kd = 1024;
  __shared__ unsigned short sm[128 * 32 + 32 * 128];
  unsigned short* As = sm;
  unsigned short* Bs = sm + 128 * 32;
  auto lds3 = (__attribute__((address_space(3))) char*)sm;

  const int tid = threadIdx.x;
  const int wave = tid >> 6, lane = tid & 63, quad = lane >> 4, l16 = lane & 15;
  const int wm = wave >> 1, wn = wave & 1;

  const int id = blockIdx.x;
  const int nid = id >> 3;
  const int by = (id & 7) * 8 + (nid & 7);
  const int bx = nid >> 3;
  const int bm = by * 128, bn = bx * 128;

  f32x4 acc[4][4] = {};

  for (int k0 = 0; k0 < Kd; k0 += 32) {
#pragma unroll
    for (int j = 0; j < 2; ++j) {
      int i = (wave * 2 + j) * 64 + lane;  // 16B-chunk index 0..511
      const unsigned short* ga = A + (size_t)(bm + (i >> 2)) * Kd + k0 + (i & 3) * 8;
      __builtin_amdgcn_global_load_lds(
          (const __attribute__((address_space(1))) void*)ga,
          (__attribute__((address_space(3))) void*)(lds3 + (size_t)(wave * 2 + j) * 1024),
          16, 0, 0);
      const unsigned short* gb = Bt + (size_t)(bn + (i >> 2)) * Kd + k0 + (i & 3) * 8;
      __builtin_amdgcn_global_load_lds(
          (const __attribute__((address_space(1))) void*)gb,
          (__attribute__((address_space(3))) void*)(lds3 + 8192 + (size_t)(wave * 2 + j) * 1024),
          16, 0, 0);
    }
    __syncthreads();

    bf16x8 af[4], bfv[4];
#pragma unroll
    for (int i = 0; i < 4; ++i)
      af[i] = *(const bf16x8*)(As + (wm * 64 + i * 16 + l16) * 32 + quad * 8);
#pragma unroll
    for (int n = 0; n < 4; ++n)
      bfv[n] = *(const bf16x8*)(Bs + (wn * 64 + n * 16 + l16) * 32 + quad * 8);
#pragma unroll
    for (int i = 0; i < 4; ++i)
#pragma unroll
      for (int n = 0; n < 4; ++n)
        acc[i][n] = MFMA16(af[i], bfv[n], acc[i][n]);
    __syncthreads();
  }

  // epilogue: C/D layout col=lane&15, row=quad*4+reg
  const int mb = bn >> 10;  // matrix id for MODE 1 (block never straddles: 1024%128==0)
  const float* bias = (MODE == 0) ? b0 : (mb == 0 ? b0 : (mb == 1 ? b1 : b2));
  const float scale = (MODE == 1 && mb == 0) ? QSCALE : 1.0f;
  unsigned short* oq = (MODE == 1) ? ((unsigned short*)out + (size_t)mb * 8388608u) : nullptr;

#pragma unroll
  for (int i = 0; i < 4; ++i) {
    const int row0 = bm + wm * 64 + i * 16 + quad * 4;
#pragma unroll
    for (int n = 0; n < 4; ++n) {
      const int col = bn + wn * 64 + n * 16 + l16;
      const int cl = col & 1023;
      const float bv = bias[cl];
      if (MODE == 1 && mb == 2) {
        // V^T: vtg[(b*16+h)][hd][s], 4 consecutive s per thread -> 8B store
        const int h = cl >> 6, hd = cl & 63;
        const int b = row0 >> 11, s0v = row0 & 2047;
        ushort4 pk;
        pk.x = f2bf(acc[i][n][0] + bv);
        pk.y = f2bf(acc[i][n][1] + bv);
        pk.z = f2bf(acc[i][n][2] + bv);
        pk.w = f2bf(acc[i][n][3] + bv);
        *(ushort4*)(vtg + (size_t)(b * 16 + h) * 131072 + (size_t)hd * 2048 + s0v) = pk;
      } else {
#pragma unroll
        for (int r = 0; r < 4; ++r) {
          float v = (acc[i][n][r] + bv) * scale;
          if (MODE == 0) {
            ((float*)out)[(size_t)(row0 + r) * 1024 + col] = v;
          } else {
            int rr = row0 + r;
            int b = rr >> 11, s = rr & 2047;
            int h = cl >> 6, hd = cl & 63;
            oq[((size_t)(b * 16 + h) * 2048 + s) * 64 + hd] = f2bf(v);
          }
        }
      }
    }
  }
}

// ---------------------------------------------------------------- flash attention
// Q pre-scaled. 512 flat blocks; block = (b,h) x 256 q-rows; wave = 64 q-rows
// (4 subtiles). XCD-grouped decode: bh = (id&7)*8 + ((id>>3)>>3) so all 8
// q-blocks of a head (and 8 whole heads) land on one XCD -> K/Vt L2-resident
// (proven R2/R3: FETCH 139 -> 25.7 MB). No setprio: lockstep loop (m190/R3).
// S^T = K(A) @ Q^T(B): C-layout puts col=l16=qrow, so each lane's 16 exp2'd
// scores (keys quad*4+r per subtile) form PV A-frags directly under the key
// permutation sigma(q*8+j) = st*32 + (j>>2)*16 + q*4 + (j&3); V B-frags use
// the same sigma (two contiguous b64 chunks from the Vt tile). No P in LDS.
__global__ __launch_bounds__(256, 2) void attn_kernel(const unsigned short* __restrict__ Q,
                                                      const unsigned short* __restrict__ K,
                                                      const unsigned short* __restrict__ Vt,
                                                      unsigned short* __restrict__ ctx) {
  const int tid = threadIdx.x;
  const int wave = tid >> 6, lane = tid & 63, quad = lane >> 4, l16 = lane & 15;

  const int id = blockIdx.x;
  const int bh = (id & 7) * 8 + ((id >> 3) >> 3);  // 8 heads per XCD
  const int qx = (id >> 3) & 7;

  // stride 72 ushorts = 36 dwords == 4 mod 32 -> conflict-free-ish frag reads
  // double buffer: [buf][Ks 64*72 | Vts 64*72]
  __shared__ unsigned short sm[2][2 * 64 * 72];

  const size_t hb = (size_t)bh * 131072;
  const int q0 = qx * 256 + wave * 64;

  // Q B-frags: B[k=hd][n=qrow]: lane l16 = qrow, k = quad*8+j (+32*st)
  bf16x8 qf[4][2];
#pragma unroll
  for (int qt = 0; qt < 4; ++qt)
#pragma unroll
    for (int st = 0; st < 2; ++st)
      qf[qt][st] = *(const bf16x8*)(Q + hb + (size_t)(q0 + qt * 16 + l16) * 64 + st * 32 + quad * 8);

  f32x4 o[4][4] = {};
  float lacc[4] = {0.f, 0.f, 0.f, 0.f};

  // staging: 4 x 16B chunks/thread (2 K rows-of-keys + 2 Vt rows-of-hd)
  const int c0 = tid, c1 = tid + 256;
  const unsigned short* gK0 = K + hb + (size_t)(c0 >> 3) * 64 + (c0 & 7) * 8;
  const unsigned short* gK1 = K + hb + (size_t)(c1 >> 3) * 64 + (c1 & 7) * 8;
  const unsigned short* gV0 = Vt + hb + (size_t)(c0 >> 3) * 2048 + (c0 & 7) * 8;
  const unsigned short* gV1 = Vt + hb + (size_t)(c1 >> 3) * 2048 + (c1 & 7) * 8;
  const int sKo = (c0 >> 3) * 72 + (c0 & 7) * 8;
  const int sKo1 = (c1 >> 3) * 72 + (c1 & 7) * 8;

  u32x4 pk0 = *(const u32x4*)gK0, pk1 = *(const u32x4*)gK1;
  u32x4 pv0 = *(const u32x4*)gV0, pv1 = *(const u32x4*)gV1;
  {
    unsigned short* s0b = sm[0];
    *(u32x4*)(s0b + sKo) = pk0; *(u32x4*)(s0b + sKo1) = pk1;
    *(u32x4*)(s0b + 4608 + sKo) = pv0; *(u32x4*)(s0b + 4608 + sKo1) = pv1;
  }
  __syncthreads();

  for (int kb = 0; kb < 2048; kb += 64) {
    const int cur = (kb >> 6) & 1;
    const bool more = (kb + 64) < 2048;
    if (more) {
      pk0 = *(const u32x4*)(gK0 + (size_t)(kb + 64) * 64);
      pk1 = *(const u32x4*)(gK1 + (size_t)(kb + 64) * 64);
      pv0 = *(const u32x4*)(gV0 + kb + 64);
      pv1 = *(const u32x4*)(gV1 + kb + 64);
    }
    const unsigned short* Ks = sm[cur];
    const unsigned short* Vts = sm[cur] + 4608;

    // K A-frags: A[m=key][k=hd]: lane l16 = key (per subtile ks), contiguous hd
    bf16x8 kf[4][2];
#pragma unroll
    for (int ks = 0; ks < 4; ++ks)
#pragma unroll
      for (int st = 0; st < 2; ++st)
        kf[ks][st] = *(const bf16x8*)(Ks + (ks * 16 + l16) * 72 + st * 32 + quad * 8);

    // V B-frags under sigma: two b64 chunks (keys st*32+quad*4+{0..3}, +16)
    bf16x8 vf[4][2];
#pragma unroll
    for (int os = 0; os < 4; ++os)
#pragma unroll
      for (int st = 0; st < 2; ++st) {
        const unsigned short* rb = Vts + (os * 16 + l16) * 72 + st * 32 + quad * 4;
        bf16x4 a = *(const bf16x4*)rb;
        bf16x4 b2 = *(const bf16x4*)(rb + 16);
        vf[os][st] = __builtin_shufflevector(a, b2, 0, 1, 2, 3, 4, 5, 6, 7);
      }

#pragma unroll
    for (int qt = 0; qt < 4; ++qt) {
      // S^T tiles: rows = keys (quad*4+r), cols = qrows (l16)
      f32x4 sc[4];
#pragma unroll
      for (int ks = 0; ks < 4; ++ks) {
        f32x4 a = {0.f, 0.f, 0.f, 0.f};
        a = MFMA16(kf[ks][0], qf[qt][0], a);
        a = MFMA16(kf[ks][1], qf[qt][1], a);
        sc[ks] = a;
      }
      // exp2 -> P A-frags in-register; per-lane l partials (all for qrow l16)
      bf16x8 pf[2];
      float ls = 0.f;
#pragma unroll
      for (int ks = 0; ks < 4; ++ks)
#pragma unroll
        for (int r = 0; r < 4; ++r) {
          float p = __builtin_amdgcn_exp2f(sc[ks][r]);
          ls += p;
          pf[ks >> 1][(ks & 1) * 4 + r] = (__bf16)p;
        }
      lacc[qt] += ls;
#pragma unroll
      for (int st = 0; st < 2; ++st)
#pragma unroll
        for (int os = 0; os < 4; ++os)
          o[qt][os] = MFMA16(pf[st], vf[os][st], o[qt][os]);
    }

    if (more) {
      unsigned short* sn = sm[cur ^ 1];
      *(u32x4*)(sn + sKo) = pk0; *(u32x4*)(sn + sKo1) = pk1;
      *(u32x4*)(sn + 4608 + sKo) = pv0; *(u32x4*)(sn + 4608 + sKo1) = pv1;
    }
    __syncthreads();
  }

  // finalize: reduce l across quads (lane's l16 = qrow), redistribute to
  // C-layout rows (quad*4+r), normalize, store.
  const int b = bh >> 4, h = bh & 15;
#pragma unroll
  for (int qt = 0; qt < 4; ++qt) {
    float l = lacc[qt];
    l += __shfl_xor(l, 16, 64);
    l += __shfl_xor(l, 32, 64);
#pragma unroll
    for (int r = 0; r < 4; ++r) {
      float lr = __shfl(l, quad * 4 + r, 16);
      float inv = 1.0f / lr;
      int s = q0 + qt * 16 + quad * 4 + r;
#pragma unroll
      for (int os = 0; os < 4; ++os)
        ctx[((size_t)(b * 2048 + s)) * 1024 + h * 64 + os * 16 + l16] = f2bf(o[qt][os][r] * inv);
    }
  }
}

// ---------------------------------------------------------------- launch
extern "C" void kernel_launch(void* const* d_in, const int* in_sizes, int n_in,
                              void* d_out, int out_size, void* d_ws, size_t ws_size,
                              hipStream_t stream) {
  const float* x  = (const float*)d_in[0];
  const float* Wq = (const float*)d_in[1];
  const float* bq = (const float*)d_in[2];
  const float* Wk = (const float*)d_in[3];
  const float* bk = (const float*)d_in[4];
  const float* Wv = (const float*)d_in[5];
  const float* bv = (const float*)d_in[6];
  const float* Wo = (const float*)d_in[7];
  const float* bo = (const float*)d_in[8];

  unsigned short* ws = (unsigned short*)d_ws;
  unsigned short* xb    = ws;                    // 8388608  A input; attn out after QKV
  unsigned short* Wtall = ws + 8388608;          // 4*1048576 (Wq^T|Wk^T|Wv^T|Wo^T)
  unsigned short* Wot   = Wtall + 3145728;
  unsigned short* Qb    = Wtall + 4194304;       // 8388608  [bh][s][hd], pre-scaled
  unsigned short* Kb    = Qb + 8388608;          // 8388608  [bh][s][hd]
  unsigned short* VtG   = Kb + 8388608;          // 8388608  [bh][hd][s] (written by QKV epilogue)
  unsigned short* Cb    = xb;                    // alias: xb dead after QKV GEMM

  cast_x_kernel<<<8192, 256, 0, stream>>>(x, xb, 2097152);
  transpose_cast4<<<dim3(32, 32, 4), dim3(32, 8), 0, stream>>>(Wq, Wk, Wv, Wo, Wtall);

  gemm128<1><<<dim3(1536), 256, 0, stream>>>(xb, Wtall, bq, bk, bv, Qb, VtG);
  attn_kernel<<<dim3(512), 256, 0, stream>>>(Qb, Kb, VtG, Cb);
  gemm128<0><<<dim3(512), 256, 0, stream>>>(Cb, Wot, bo, nullptr, nullptr, d_out, nullptr);
}